// Round 4
// baseline (196.059 us; speedup 1.0000x reference)
//
#include <hip/hip_runtime.h>
#include <stdint.h>

#define N_TOK  16384
#define EMB    512
#define NEMB   2048
#define NCHUNK 32            // 64 templates per chunk
#define CWIN   2.5e-4f       // ref-f32-grid + bf16 score-noise margin (passed R5-R7)
#define WCAP   524288

typedef __attribute__((ext_vector_type(8))) short s16x8;
typedef __attribute__((ext_vector_type(4))) float f32x4;

__device__ __forceinline__ unsigned short f2bf(float f) {   // RNE f32 -> bf16
  unsigned u = __float_as_uint(f);
  u += 0x7fffu + ((u >> 16) & 1u);
  return (unsigned short)(u >> 16);
}
// monotone f32 -> u32 (total order, NaN sorts above all reals)
__device__ __forceinline__ unsigned mapf(float f) {
  unsigned u = __float_as_uint(f);
  return (u >> 31) ? ~u : (u | 0x80000000u);
}
__device__ __forceinline__ float unmapf(unsigned u) {
  return __uint_as_float((u >> 31) ? (u & 0x7fffffffu) : ~u);
}

// numpy pairwise_sum emulation for sum(x*x) over 512 contiguous f32.
__device__ __forceinline__ float pairwise512_sq(const float* se, int lane) {
  int l = lane & 31;
  int b = l >> 3, j = l & 7;
  const float* base = se + b * 128 + j;
  float x = base[0];
  float r = __fmul_rn(x, x);
#pragma unroll
  for (int k = 1; k < 16; ++k) {
    float y = base[8 * k];
    r = __fadd_rn(r, __fmul_rn(y, y));
  }
  r = __fadd_rn(r, __shfl_xor(r, 1));
  r = __fadd_rn(r, __shfl_xor(r, 2));
  r = __fadd_rn(r, __shfl_xor(r, 4));
  r = __fadd_rn(r, __shfl_xor(r, 8));
  r = __fadd_rn(r, __shfl_xor(r, 16));
  return r;
}

// ---------- kernel 1: fused prep, 4 rows per block (wave per row) ----------
__global__ __launch_bounds__(256) void prep_kernel(
    const float* __restrict__ tmp, const float* __restrict__ enc,
    unsigned short* __restrict__ thi, float* __restrict__ tsq,
    unsigned short* __restrict__ ehi, float* __restrict__ esq,
    int* __restrict__ wcount) {
  __shared__ float se[4][EMB];
  int wv = threadIdx.x >> 6, lane = threadIdx.x & 63;
  int row = blockIdx.x * 4 + wv;                             // 18432 rows
  if (blockIdx.x == 0 && threadIdx.x == 0) *wcount = 0;
  bool isT = row < NEMB;
  const float* src = isT ? (tmp + (size_t)row * EMB)
                         : (enc + (size_t)(row - NEMB) * EMB);
  const float4* p = (const float4*)src + lane * 2;
  float4 v0 = p[0], v1 = p[1];
  float f[8] = {v0.x, v0.y, v0.z, v0.w, v1.x, v1.y, v1.z, v1.w};
  unsigned h[8];
#pragma unroll
  for (int i = 0; i < 8; ++i) { h[i] = f2bf(f[i]); se[wv][lane * 8 + i] = f[i]; }
  uint4 packed = { h[0] | (h[1] << 16), h[2] | (h[3] << 16),
                   h[4] | (h[5] << 16), h[6] | (h[7] << 16) };
  unsigned short* dsth = isT ? (thi + (size_t)row * EMB)
                             : (ehi + (size_t)(row - NEMB) * EMB);
  ((uint4*)dsth)[lane] = packed;
  __syncthreads();
  float s = pairwise512_sq(se[wv], lane);
  if (lane == 0) { if (isT) tsq[row] = s; else esq[row - NEMB] = s; }
}

// ---------- kernel 2: 256x256-tile 8-wave phased GEMM (T2+T3+T4+T5) ----------
// EXACT R1 kernel (measured 57 us: VGPR 112, 0 bank conflicts, no spill).
// R3's XCD-locality remap regressed 57->100 us: it concentrated all
// co-resident blocks of an XCD on a 4 MB hot set with identical address
// streams (near-lockstep K-loops) -> L2 same-line request storms serialize,
// and the vmcnt-counted phases stall on burst latency. TCC FETCH dropped to
// compulsory (17 MB) but time doubled: L2-miss VOLUME was never the
// bottleneck at 17% HBM peak. Default mapping (consecutive bids share an
// A-panel across DIFFERENT XCDs; each XCD streams distinct addresses, L3
// absorbs cross-XCD re-reads) is the proven best -> reverted, no other edits.
// K = 512 = 8 K-tiles of BK=64; each K-tile = two 32-wide kk panels.
// LDS 128 KiB, st_16x32 swizzle via inverse-swizzled global source (linear
// global_load_lds dest) + swizzled ds_read. vmcnt ledger: waits of 8 (steady),
// 4/0 (drain) before barriers; never drains mid-loop.
// MFMA order per acc element: kt ascending, kk0 then kk1 -> scores
// BIT-IDENTICAL to R1/R2/R3; downstream CWIN/refine logic unchanged.
__global__ __launch_bounds__(512, 2) void score_kernel(
    const unsigned short* __restrict__ ehi, const unsigned short* __restrict__ thi,
    const float* __restrict__ tsq,
    unsigned long long* __restrict__ keyc, unsigned* __restrict__ s2c) {
  __shared__ __align__(16) char smem[131072];
  const int tid = threadIdx.x, w = tid >> 6, lane = tid & 63;
  const int q = lane >> 4, r = lane & 15;
  const int wr = w >> 2, wc = w & 3;               // 2M x 4N wave grid
  const int tokb = (int)blockIdx.x >> 3;           // 64
  const int nb   = (int)blockIdx.x & 7;            // 8

  // ---- per-thread stage-source precompute (inverse swizzle of linear dest) ----
  const int c0 = tid, c1 = 512 + tid;
  const int L0 = (c0 * 16) ^ ((((c0 * 16) >> 9) & 1) << 5);
  const int L1 = (c1 * 16) ^ ((((c1 * 16) >> 9) & 1) << 5);
  const int row0 = L0 >> 6, ce0 = (L0 & 63) >> 1;
  const int row1 = L1 >> 6, ce1 = (L1 & 63) >> 1;
  const unsigned short* pa0 = ehi + (size_t)(tokb * 256 + row0) * EMB + ce0;
  const unsigned short* pa1 = ehi + (size_t)(tokb * 256 + row1) * EMB + ce1;
  const unsigned short* pb0 = thi + (size_t)(nb  * 256 + row0) * EMB + ce0;
  const unsigned short* pb1 = thi + (size_t)(nb  * 256 + row1) * EMB + ce1;

#define STAGE_A(ktp, kk) do {                                                     \
    char* lb_ = smem + ((((ktp) & 1) * 2 + (kk)) << 14) + (w << 10);              \
    __builtin_amdgcn_global_load_lds(                                             \
        (const __attribute__((address_space(1))) void*)(pa0 + (ktp) * 64 + (kk) * 32), \
        (__attribute__((address_space(3))) void*)lb_, 16, 0, 0);                  \
    __builtin_amdgcn_global_load_lds(                                             \
        (const __attribute__((address_space(1))) void*)(pa1 + (ktp) * 64 + (kk) * 32), \
        (__attribute__((address_space(3))) void*)(lb_ + 8192), 16, 0, 0);         \
  } while (0)
#define STAGE_B(ktp, kk) do {                                                     \
    char* lb_ = smem + 65536 + ((((ktp) & 1) * 2 + (kk)) << 14) + (w << 10);      \
    __builtin_amdgcn_global_load_lds(                                             \
        (const __attribute__((address_space(1))) void*)(pb0 + (ktp) * 64 + (kk) * 32), \
        (__attribute__((address_space(3))) void*)lb_, 16, 0, 0);                  \
    __builtin_amdgcn_global_load_lds(                                             \
        (const __attribute__((address_space(1))) void*)(pb1 + (ktp) * 64 + (kk) * 32), \
        (__attribute__((address_space(3))) void*)(lb_ + 8192), 16, 0, 0);         \
  } while (0)

  // ---- swizzled fragment-read offsets (within a 16 KB panel) ----
  int offA[8], offB[4];
#pragma unroll
  for (int m = 0; m < 8; ++m) {
    int P = (wr * 128 + m * 16 + r) * 64 + q * 16;
    offA[m] = P ^ (((P >> 9) & 1) << 5);
  }
#pragma unroll
  for (int n = 0; n < 4; ++n) {
    int P = (wc * 64 + n * 16 + r) * 64 + q * 16;
    offB[n] = P ^ (((P >> 9) & 1) << 5);
  }

  f32x4 acc[8][4];
#pragma unroll
  for (int m = 0; m < 8; ++m)
#pragma unroll
    for (int n = 0; n < 4; ++n) acc[m][n] = (f32x4){0.f, 0.f, 0.f, 0.f};

  // ---- prologue: kt0 all 4 panels + kt1 kk0 panels (units #1..#6) ----
  STAGE_A(0, 0); STAGE_B(0, 0); STAGE_A(0, 1); STAGE_B(0, 1); STAGE_A(1, 0); STAGE_B(1, 0);
  asm volatile("s_waitcnt vmcnt(8)" ::: "memory");   // units 1,2 (kk0 of kt0) landed
  __builtin_amdgcn_s_barrier();

#define LOADA(kkbase, mh)                                        \
    a0 = *(const s16x8*)(Ab_ + (kkbase) + offA[(mh) * 4 + 0]);   \
    a1 = *(const s16x8*)(Ab_ + (kkbase) + offA[(mh) * 4 + 1]);   \
    a2 = *(const s16x8*)(Ab_ + (kkbase) + offA[(mh) * 4 + 2]);   \
    a3 = *(const s16x8*)(Ab_ + (kkbase) + offA[(mh) * 4 + 3]);
#define LOADB(kkbase)                                            \
    bf4[0] = *(const s16x8*)(Bb_ + (kkbase) + offB[0]);          \
    bf4[1] = *(const s16x8*)(Bb_ + (kkbase) + offB[1]);          \
    bf4[2] = *(const s16x8*)(Bb_ + (kkbase) + offB[2]);          \
    bf4[3] = *(const s16x8*)(Bb_ + (kkbase) + offB[3]);
#define MFMA_HALF(mh)                                                              \
    __builtin_amdgcn_s_setprio(1);                                                 \
    _Pragma("unroll")                                                              \
    for (int n = 0; n < 4; ++n) {                                                  \
      acc[(mh) * 4 + 0][n] = __builtin_amdgcn_mfma_f32_16x16x32_bf16(a0, bf4[n], acc[(mh) * 4 + 0][n], 0, 0, 0); \
      acc[(mh) * 4 + 1][n] = __builtin_amdgcn_mfma_f32_16x16x32_bf16(a1, bf4[n], acc[(mh) * 4 + 1][n], 0, 0, 0); \
      acc[(mh) * 4 + 2][n] = __builtin_amdgcn_mfma_f32_16x16x32_bf16(a2, bf4[n], acc[(mh) * 4 + 2][n], 0, 0, 0); \
      acc[(mh) * 4 + 3][n] = __builtin_amdgcn_mfma_f32_16x16x32_bf16(a3, bf4[n], acc[(mh) * 4 + 3][n], 0, 0, 0); \
    }                                                                              \
    __builtin_amdgcn_s_setprio(0);

#pragma unroll
  for (int kt = 0; kt < 8; ++kt) {
    char* Ab_ = smem + ((kt & 1) * 2 << 14);
    char* Bb_ = smem + 65536 + ((kt & 1) * 2 << 14);
    s16x8 a0, a1, a2, a3, bf4[4];
    // -- g1: kk0, m0-3; stage A-kk1(kt+1)
    LOADA(0, 0); LOADB(0);
    if (kt + 1 < 8) STAGE_A(kt + 1, 1);
    __builtin_amdgcn_s_barrier();
    MFMA_HALF(0);
    __builtin_amdgcn_s_barrier();
    // -- g2: kk0, m4-7; stage B-kk1(kt+1); wait for kk1(kt)
    LOADA(0, 1);
    if (kt + 1 < 8) STAGE_B(kt + 1, 1);
    __builtin_amdgcn_s_barrier();
    MFMA_HALF(1);
    if (kt < 7) { asm volatile("s_waitcnt vmcnt(8)" ::: "memory"); }
    else        { asm volatile("s_waitcnt vmcnt(0)" ::: "memory"); }
    __builtin_amdgcn_s_barrier();
    // -- g3: kk1, m0-3; stage A-kk0(kt+2)
    LOADA(16384, 0); LOADB(16384);
    if (kt + 2 < 8) STAGE_A(kt + 2, 0);
    __builtin_amdgcn_s_barrier();
    MFMA_HALF(0);
    __builtin_amdgcn_s_barrier();
    // -- g4: kk1, m4-7; stage B-kk0(kt+2); wait for kk0(kt+1)
    LOADA(16384, 1);
    if (kt + 2 < 8) STAGE_B(kt + 2, 0);
    __builtin_amdgcn_s_barrier();
    MFMA_HALF(1);
    if (kt < 6)       { asm volatile("s_waitcnt vmcnt(8)" ::: "memory"); }
    else if (kt == 6) { asm volatile("s_waitcnt vmcnt(4)" ::: "memory"); }
    __builtin_amdgcn_s_barrier();
  }

  // ---- epilogue: in-register argmin; wave (wr,wc) owns tokens wr*128..+127
  // of chunk nb*4+wc. Butterfly over r (16 template cols per fragment).
  const int chunk = nb * 4 + wc;
  const int nbase = nb * 256 + wc * 64;
  float tq[4];
#pragma unroll
  for (int n = 0; n < 4; ++n) tq[n] = tsq[nbase + n * 16 + r];
#pragma unroll
  for (int m = 0; m < 8; ++m) {
#pragma unroll
    for (int i = 0; i < 4; ++i) {
      unsigned long long k1 = ~0ULL; unsigned s2m = 0xffffffffu;
#pragma unroll
      for (int n = 0; n < 4; ++n) {                 // n ascending = template ascending
        float s = tq[n] - 2.0f * acc[m][n][i];
        unsigned sm = mapf(s);
        unsigned long long k =
            ((unsigned long long)sm << 32) | (unsigned)(nbase + n * 16 + r);
        if (k < k1) { unsigned o = (unsigned)(k1 >> 32); s2m = o < s2m ? o : s2m; k1 = k; }
        else s2m = sm < s2m ? sm : s2m;
      }
#pragma unroll
      for (int mask = 1; mask < 16; mask <<= 1) {
        unsigned long long ok = __shfl_xor(k1, mask);
        unsigned os = __shfl_xor(s2m, mask);
        if (ok < k1) { unsigned o = (unsigned)(k1 >> 32); s2m = o < s2m ? o : s2m; k1 = ok; }
        else { unsigned o = (unsigned)(ok >> 32); s2m = o < s2m ? o : s2m; }
        s2m = os < s2m ? os : s2m;
      }
      if (r == 0) {
        int token = tokb * 256 + wr * 128 + m * 16 + q * 4 + i;
        keyc[(size_t)chunk * N_TOK + token] = k1;
        s2c [(size_t)chunk * N_TOK + token] = s2m;
      }
    }
  }
#undef STAGE_A
#undef STAGE_B
#undef LOADA
#undef LOADB
#undef MFMA_HALF
}

// ---------- kernel 3: 32-way key merge, flag, worklist; inits rkey ----------
__global__ __launch_bounds__(256) void merge_kernel(
    const unsigned long long* __restrict__ keyc, const unsigned* __restrict__ s2c,
    int* __restrict__ bestIdx, int* __restrict__ flag, int* __restrict__ work,
    int* __restrict__ wcount, unsigned long long* __restrict__ rkey) {
  int t = blockIdx.x * 256 + threadIdx.x;
  if (t >= N_TOK) return;
  rkey[t] = ~0ULL;
  unsigned long long K = ~0ULL; unsigned S = 0xffffffffu;
  for (int c = 0; c < NCHUNK; ++c) {
    unsigned long long k = keyc[(size_t)c * N_TOK + t];
    unsigned s2 = s2c[(size_t)c * N_TOK + t];
    if (k < K) { unsigned o = (unsigned)(K >> 32); S = o < S ? o : S; K = k; }
    else { unsigned o = (unsigned)(k >> 32); S = o < S ? o : S; }
    S = s2 < S ? s2 : S;
  }
  float best_f   = unmapf((unsigned)(K >> 32));
  float second_f = unmapf(S);
  int idx = (int)(unsigned)(K & 0xffffffffu);
  bestIdx[t] = idx;
  bool ok = (second_f - best_f >= CWIN) && (idx >= 0) && (idx < NEMB) && (best_f == best_f);
  flag[t] = ok ? 0 : 1;
  if (!ok) {
    bool nanCase = !(best_f == best_f);
    float limit = best_f + CWIN;
    for (int c = 0; c < NCHUNK; ++c) {
      float cf = unmapf((unsigned)(keyc[(size_t)c * N_TOK + t] >> 32));
      if (nanCase || !(cf > limit)) {               // NaN-safe candidate test
        int pos = atomicAdd(wcount, 1);
        if (pos < WCAP) work[pos] = t * NCHUNK + c;
      }
    }
  }
}

// ---------- kernel 4: f32-emulated rescan, 16 lanes per template ----------
// 4 templates per wave in parallel (group g = lane>>4); double accumulation is
// associativity-equivalent to the previous 64-lane tree (rounds once to f32).
__global__ __launch_bounds__(256) void refine_kernel(
    const float* __restrict__ enc, const float* __restrict__ tmp,
    const float* __restrict__ esq, const float* __restrict__ tsq,
    const int* __restrict__ work, const int* __restrict__ wcount,
    unsigned long long* __restrict__ rkey) {
  int total = *wcount; if (total > WCAP) total = WCAP;
  __shared__ float se[EMB];
  const int wv = threadIdx.x >> 6, lane = threadIdx.x & 63;
  const int g = lane >> 4, l16 = lane & 15;
  for (int p = blockIdx.x; p < total; p += gridDim.x) {
    __syncthreads();
    int item = work[p];
    int token = item / NCHUNK, c = item % NCHUNK;
    const float4* erow = (const float4*)(enc + (size_t)token * EMB);
    for (int i = threadIdx.x; i < 128; i += 256) ((float4*)se)[i] = erow[i];
    __syncthreads();
    float e2 = esq[token];
    unsigned long long lkey = ~0ULL;
#pragma unroll
    for (int j = 0; j < 4; ++j) {
      int m = c * 64 + wv * 16 + j * 4 + g;
      const float4* trow = (const float4*)(tmp + (size_t)m * EMB);
      double s = 0.0;
#pragma unroll
      for (int k = 0; k < 8; ++k) {
        float4 a = trow[l16 + 16 * k];
        float4 b = ((const float4*)se)[l16 + 16 * k];
        s += (double)a.x * b.x + (double)a.y * b.y
           + (double)a.z * b.z + (double)a.w * b.w;
      }
      s += __shfl_xor(s, 1); s += __shfl_xor(s, 2);
      s += __shfl_xor(s, 4); s += __shfl_xor(s, 8);
      if (l16 == 0) {
        float M  = (float)s;
        float d1 = __fadd_rn(e2, -__fmul_rn(2.0f, M));
        float d2 = __fadd_rn(d1, tsq[m]);            // full dist >= 0: bits monotone
        unsigned long long key =
            ((unsigned long long)__float_as_uint(d2) << 32) | (unsigned)m;
        if (key < lkey) lkey = key;
      }
    }
    if (l16 == 0 && lkey != ~0ULL) atomicMin(&rkey[token], lkey);
  }
}

// ---------- kernel 5: gather f32 rows + zidx as f32 ----------
__global__ void gather_kernel(const float* __restrict__ tmp, const int* __restrict__ bestIdx,
                              const int* __restrict__ flag,
                              const unsigned long long* __restrict__ rkey,
                              float* __restrict__ out) {
  int token = blockIdx.x * 4 + (threadIdx.x >> 6);
  int lane = threadIdx.x & 63;
  int idx = flag[token] ? (int)(unsigned)(rkey[token] & 0xffffffffULL) : bestIdx[token];
  idx = idx < 0 ? 0 : (idx > NEMB - 1 ? NEMB - 1 : idx);
  const float4* src = (const float4*)(tmp + (size_t)idx * EMB) + lane * 2;
  float4* dst = (float4*)(out + (size_t)token * EMB) + lane * 2;
  dst[0] = src[0];
  dst[1] = src[1];
  if (lane == 0) out[(size_t)N_TOK * EMB + token] = (float)idx;
}

extern "C" void kernel_launch(void* const* d_in, const int* in_sizes, int n_in,
                              void* d_out, int out_size, void* d_ws, size_t ws_size,
                              hipStream_t stream) {
  const float* enc = (const float*)d_in[0];
  const float* tmp = (const float*)d_in[1];
  float* out = (float*)d_out;
  char* ws = (char*)d_ws;
  unsigned short* thi = (unsigned short*)ws;                 //  2,097,152 B
  unsigned short* ehi = (unsigned short*)(ws + 2097152);     // 16,777,216 B
  float* tsq      = (float*)(ws + 18874368);                 //      8,192 B
  float* esq      = (float*)(ws + 18882560);                 //     65,536 B
  unsigned long long* keyc = (unsigned long long*)(ws + 18948096); // 4,194,304 B
  unsigned* s2c   = (unsigned*)(ws + 23142400);              //  2,097,152 B
  int*   bestIdx  = (int*)  (ws + 25239552);                 //     65,536 B
  int*   flag     = (int*)  (ws + 25305088);                 //     65,536 B
  unsigned long long* rkey = (unsigned long long*)(ws + 25370624); // 131,072 B
  int*   wcount   = (int*)  (ws + 25501696);                 //         64 B
  int*   work     = (int*)  (ws + 25501760);                 //  2,097,152 B

  prep_kernel  <<<4608,      256, 0, stream>>>(tmp, enc, thi, tsq, ehi, esq, wcount);
  score_kernel <<<512,       512, 0, stream>>>(ehi, thi, tsq, keyc, s2c);
  merge_kernel <<<N_TOK/256, 256, 0, stream>>>(keyc, s2c, bestIdx, flag, work, wcount, rkey);
  refine_kernel<<<1024,      256, 0, stream>>>(enc, tmp, esq, tsq, work, wcount, rkey);
  gather_kernel<<<N_TOK/4,   256, 0, stream>>>(tmp, bestIdx, flag, rkey, out);
}

// Round 5
// 192.565 us; speedup vs baseline: 1.0181x; 1.0181x over previous
//
#include <hip/hip_runtime.h>
#include <stdint.h>

#define N_TOK  16384
#define EMB    512
#define NEMB   2048
#define NCHUNK 32            // 64 templates per chunk
#define CWIN   2.5e-4f       // ref-f32-grid + bf16 score-noise margin (passed R5-R7)
#define WCAP   524288

typedef __attribute__((ext_vector_type(8))) short s16x8;
typedef __attribute__((ext_vector_type(4))) float f32x4;

__device__ __forceinline__ unsigned short f2bf(float f) {   // RNE f32 -> bf16
  unsigned u = __float_as_uint(f);
  u += 0x7fffu + ((u >> 16) & 1u);
  return (unsigned short)(u >> 16);
}
// monotone f32 -> u32 (total order, NaN sorts above all reals)
__device__ __forceinline__ unsigned mapf(float f) {
  unsigned u = __float_as_uint(f);
  return (u >> 31) ? ~u : (u | 0x80000000u);
}
__device__ __forceinline__ float unmapf(unsigned u) {
  return __uint_as_float((u >> 31) ? (u & 0x7fffffffu) : ~u);
}

// numpy pairwise_sum emulation for sum(x*x) over 512 contiguous f32.
__device__ __forceinline__ float pairwise512_sq(const float* se, int lane) {
  int l = lane & 31;
  int b = l >> 3, j = l & 7;
  const float* base = se + b * 128 + j;
  float x = base[0];
  float r = __fmul_rn(x, x);
#pragma unroll
  for (int k = 1; k < 16; ++k) {
    float y = base[8 * k];
    r = __fadd_rn(r, __fmul_rn(y, y));
  }
  r = __fadd_rn(r, __shfl_xor(r, 1));
  r = __fadd_rn(r, __shfl_xor(r, 2));
  r = __fadd_rn(r, __shfl_xor(r, 4));
  r = __fadd_rn(r, __shfl_xor(r, 8));
  r = __fadd_rn(r, __shfl_xor(r, 16));
  return r;
}

// ---------- kernel 1: fused prep, 4 rows per block (wave per row) ----------
__global__ __launch_bounds__(256) void prep_kernel(
    const float* __restrict__ tmp, const float* __restrict__ enc,
    unsigned short* __restrict__ thi, float* __restrict__ tsq,
    unsigned short* __restrict__ ehi, float* __restrict__ esq,
    int* __restrict__ wcount) {
  __shared__ float se[4][EMB];
  int wv = threadIdx.x >> 6, lane = threadIdx.x & 63;
  int row = blockIdx.x * 4 + wv;                             // 18432 rows
  if (blockIdx.x == 0 && threadIdx.x == 0) *wcount = 0;
  bool isT = row < NEMB;
  const float* src = isT ? (tmp + (size_t)row * EMB)
                         : (enc + (size_t)(row - NEMB) * EMB);
  const float4* p = (const float4*)src + lane * 2;
  float4 v0 = p[0], v1 = p[1];
  float f[8] = {v0.x, v0.y, v0.z, v0.w, v1.x, v1.y, v1.z, v1.w};
  unsigned h[8];
#pragma unroll
  for (int i = 0; i < 8; ++i) { h[i] = f2bf(f[i]); se[wv][lane * 8 + i] = f[i]; }
  uint4 packed = { h[0] | (h[1] << 16), h[2] | (h[3] << 16),
                   h[4] | (h[5] << 16), h[6] | (h[7] << 16) };
  unsigned short* dsth = isT ? (thi + (size_t)row * EMB)
                             : (ehi + (size_t)(row - NEMB) * EMB);
  ((uint4*)dsth)[lane] = packed;
  __syncthreads();
  float s = pairwise512_sq(se[wv], lane);
  if (lane == 0) { if (isT) tsq[row] = s; else esq[row - NEMB] = s; }
}

// ---------- kernel 2: 128x128-tile, 4-wave, 3-deep counted-vmcnt GEMM ----------
// REDESIGN for cross-session latency robustness. R1-structure (1 block/CU,
// 128 KiB LDS, barrier-lockstep) ran 57 us in one session and 101 us in
// another (identical code+counters; achieved BW 1323 vs 747 GB/s): with one
// block per CU, every vmcnt wait exposes raw L2/L3 latency. Fix = TLP + depth:
//  - 128x128 tile, 256 thr (2x2 waves, 64x64/wave, acc[4][4]).
//  - K-step 32: panels A,B = 128x32 bf16 = 8 KB; ring of 3 buffers/operand
//    = 48 KiB LDS -> 3 blocks/CU (12 waves/CU): other blocks compute while
//    one stalls.
//  - counted vmcnt: stage panel t+2 while computing t; wait vmcnt(4) (never
//    0 mid-loop). WAR safe: STAGE(t+2) targets buf[(t-1)%3], whose reads
//    finished before the barrier ending iter t-1.
//  - granule-XOR swizzle P ^= ((P>>7)&3)<<4 (involution on 16B granules;
//    bits 7:8 = row[2:1] unchanged by the XOR). Read banks: group bits[6:4]
//    = {row0, q^row[2:1]} -> 8 lanes/group = conflict-free. Applied as
//    inverse-swizzled GLOBAL source + linear global_load_lds dest + swizzled
//    ds_read (both-sides rule).
// Per-acc K order: t ascending, 32-chunks, same 16x16x32 intrinsic -> scores
// BIT-IDENTICAL to R0..R4. Each wave owns one 64-template chunk
// (chunk = nb*2 + wc) for its 64 tokens; same fold+butterfly epilogue.
__global__ __launch_bounds__(256, 3) void score_kernel(
    const unsigned short* __restrict__ ehi, const unsigned short* __restrict__ thi,
    const float* __restrict__ tsq,
    unsigned long long* __restrict__ keyc, unsigned* __restrict__ s2c) {
  __shared__ __align__(16) char smem[49152];       // A: 3x8 KB, B: +24576 3x8 KB
  const int tid = threadIdx.x, w = tid >> 6, lane = tid & 63;
  const int q = lane >> 4, r = lane & 15;
  const int wr = w >> 1, wc = w & 1;               // 2M x 2N wave grid
  const int tokb = (int)blockIdx.x >> 4;           // 0..127 (128 tokens each)
  const int nb   = (int)blockIdx.x & 15;           // 0..15  (128 templates each)

  // ---- stage-source precompute: thread covers 2 granule-pairs (A,B) ----
  // linear dest Lp (wave base + lane*16); logical P = Lp ^ ((Lp>>7)&3)<<4.
  const int Lp0 = w * 2048 + lane * 16;
  const int Lp1 = Lp0 + 1024;
  const int P0 = Lp0 ^ (((Lp0 >> 7) & 3) << 4);
  const int P1 = Lp1 ^ (((Lp1 >> 7) & 3) << 4);
  const int rw0 = P0 >> 6, cc0 = (P0 & 63) >> 1;
  const int rw1 = P1 >> 6, cc1 = (P1 & 63) >> 1;
  const unsigned short* paA0 = ehi + (size_t)(tokb * 128 + rw0) * EMB + cc0;
  const unsigned short* paA1 = ehi + (size_t)(tokb * 128 + rw1) * EMB + cc1;
  const unsigned short* pbB0 = thi + (size_t)(nb * 128 + rw0) * EMB + cc0;
  const unsigned short* pbB1 = thi + (size_t)(nb * 128 + rw1) * EMB + cc1;

#define GLD(src, dst)                                                    \
  __builtin_amdgcn_global_load_lds(                                      \
      (const __attribute__((address_space(1))) void*)(src),              \
      (__attribute__((address_space(3))) void*)(dst), 16, 0, 0)
#define STAGE(t) do {                                                    \
    char* da_ = smem + ((t) % 3) * 8192 + w * 2048;                      \
    char* db_ = smem + 24576 + ((t) % 3) * 8192 + w * 2048;              \
    GLD(paA0 + (t) * 32, da_);                                           \
    GLD(paA1 + (t) * 32, da_ + 1024);                                    \
    GLD(pbB0 + (t) * 32, db_);                                           \
    GLD(pbB1 + (t) * 32, db_ + 1024);                                    \
  } while (0)

  // ---- swizzled fragment-read offsets within an 8 KB panel ----
  int offA[4], offB[4];
#pragma unroll
  for (int m = 0; m < 4; ++m) {
    int row = wr * 64 + m * 16 + r;
    int P = row * 64 + q * 16;
    offA[m] = P ^ (((P >> 7) & 3) << 4);
  }
#pragma unroll
  for (int n = 0; n < 4; ++n) {
    int row = wc * 64 + n * 16 + r;
    int P = row * 64 + q * 16;
    offB[n] = P ^ (((P >> 7) & 3) << 4);
  }

  f32x4 acc[4][4];
#pragma unroll
  for (int m = 0; m < 4; ++m)
#pragma unroll
    for (int n = 0; n < 4; ++n) acc[m][n] = (f32x4){0.f, 0.f, 0.f, 0.f};

  // ---- prologue: panels 0 and 1 in flight (8 units); wait panel 0 ----
  STAGE(0); STAGE(1);
  asm volatile("s_waitcnt vmcnt(4)" ::: "memory");
  __builtin_amdgcn_s_barrier();

#pragma unroll
  for (int t = 0; t < 16; ++t) {
    const char* Ab_ = smem + (t % 3) * 8192;
    const char* Bb_ = smem + 24576 + (t % 3) * 8192;
    if (t + 2 < 16) STAGE(t + 2);                  // targets buf[(t-1)%3]: WAR-safe
    s16x8 af[4], bf[4];
#pragma unroll
    for (int m = 0; m < 4; ++m) af[m] = *(const s16x8*)(Ab_ + offA[m]);
#pragma unroll
    for (int n = 0; n < 4; ++n) bf[n] = *(const s16x8*)(Bb_ + offB[n]);
    __builtin_amdgcn_s_setprio(1);
#pragma unroll
    for (int n = 0; n < 4; ++n) {
      acc[0][n] = __builtin_amdgcn_mfma_f32_16x16x32_bf16(af[0], bf[n], acc[0][n], 0, 0, 0);
      acc[1][n] = __builtin_amdgcn_mfma_f32_16x16x32_bf16(af[1], bf[n], acc[1][n], 0, 0, 0);
      acc[2][n] = __builtin_amdgcn_mfma_f32_16x16x32_bf16(af[2], bf[n], acc[2][n], 0, 0, 0);
      acc[3][n] = __builtin_amdgcn_mfma_f32_16x16x32_bf16(af[3], bf[n], acc[3][n], 0, 0, 0);
    }
    __builtin_amdgcn_s_setprio(0);
    // ensure panel t+1 landed before the barrier (outstanding: t+1, t+2)
    if (t < 14) { asm volatile("s_waitcnt vmcnt(4)" ::: "memory"); }
    else        { asm volatile("s_waitcnt vmcnt(0)" ::: "memory"); }
    __builtin_amdgcn_s_barrier();
  }

  // ---- epilogue: in-register argmin; wave (wr,wc) owns tokens
  // tokb*128 + wr*64 .. +63 of chunk nb*2+wc. Fold n, butterfly over r.
  const int chunk = nb * 2 + wc;
  const int nbase = chunk * 64;
  float tq[4];
#pragma unroll
  for (int n = 0; n < 4; ++n) tq[n] = tsq[nbase + n * 16 + r];
#pragma unroll
  for (int m = 0; m < 4; ++m) {
#pragma unroll
    for (int i = 0; i < 4; ++i) {
      unsigned long long k1 = ~0ULL; unsigned s2m = 0xffffffffu;
#pragma unroll
      for (int n = 0; n < 4; ++n) {                 // n ascending = template ascending
        float s = tq[n] - 2.0f * acc[m][n][i];
        unsigned sm = mapf(s);
        unsigned long long k =
            ((unsigned long long)sm << 32) | (unsigned)(nbase + n * 16 + r);
        if (k < k1) { unsigned o = (unsigned)(k1 >> 32); s2m = o < s2m ? o : s2m; k1 = k; }
        else s2m = sm < s2m ? sm : s2m;
      }
#pragma unroll
      for (int mask = 1; mask < 16; mask <<= 1) {
        unsigned long long ok = __shfl_xor(k1, mask);
        unsigned os = __shfl_xor(s2m, mask);
        if (ok < k1) { unsigned o = (unsigned)(k1 >> 32); s2m = o < s2m ? o : s2m; k1 = ok; }
        else { unsigned o = (unsigned)(ok >> 32); s2m = o < s2m ? o : s2m; }
        s2m = os < s2m ? os : s2m;
      }
      if (r == 0) {
        int token = tokb * 128 + wr * 64 + m * 16 + q * 4 + i;
        keyc[(size_t)chunk * N_TOK + token] = k1;
        s2c [(size_t)chunk * N_TOK + token] = s2m;
      }
    }
  }
#undef GLD
#undef STAGE
}

// ---------- kernel 3: 32-way key merge, flag, worklist; inits rkey ----------
__global__ __launch_bounds__(256) void merge_kernel(
    const unsigned long long* __restrict__ keyc, const unsigned* __restrict__ s2c,
    int* __restrict__ bestIdx, int* __restrict__ flag, int* __restrict__ work,
    int* __restrict__ wcount, unsigned long long* __restrict__ rkey) {
  int t = blockIdx.x * 256 + threadIdx.x;
  if (t >= N_TOK) return;
  rkey[t] = ~0ULL;
  unsigned long long K = ~0ULL; unsigned S = 0xffffffffu;
  for (int c = 0; c < NCHUNK; ++c) {
    unsigned long long k = keyc[(size_t)c * N_TOK + t];
    unsigned s2 = s2c[(size_t)c * N_TOK + t];
    if (k < K) { unsigned o = (unsigned)(K >> 32); S = o < S ? o : S; K = k; }
    else { unsigned o = (unsigned)(k >> 32); S = o < S ? o : S; }
    S = s2 < S ? s2 : S;
  }
  float best_f   = unmapf((unsigned)(K >> 32));
  float second_f = unmapf(S);
  int idx = (int)(unsigned)(K & 0xffffffffu);
  bestIdx[t] = idx;
  bool ok = (second_f - best_f >= CWIN) && (idx >= 0) && (idx < NEMB) && (best_f == best_f);
  flag[t] = ok ? 0 : 1;
  if (!ok) {
    bool nanCase = !(best_f == best_f);
    float limit = best_f + CWIN;
    for (int c = 0; c < NCHUNK; ++c) {
      float cf = unmapf((unsigned)(keyc[(size_t)c * N_TOK + t] >> 32));
      if (nanCase || !(cf > limit)) {               // NaN-safe candidate test
        int pos = atomicAdd(wcount, 1);
        if (pos < WCAP) work[pos] = t * NCHUNK + c;
      }
    }
  }
}

// ---------- kernel 4: f32-emulated rescan, 16 lanes per template ----------
// 4 templates per wave in parallel (group g = lane>>4); double accumulation is
// associativity-equivalent to the previous 64-lane tree (rounds once to f32).
__global__ __launch_bounds__(256) void refine_kernel(
    const float* __restrict__ enc, const float* __restrict__ tmp,
    const float* __restrict__ esq, const float* __restrict__ tsq,
    const int* __restrict__ work, const int* __restrict__ wcount,
    unsigned long long* __restrict__ rkey) {
  int total = *wcount; if (total > WCAP) total = WCAP;
  __shared__ float se[EMB];
  const int wv = threadIdx.x >> 6, lane = threadIdx.x & 63;
  const int g = lane >> 4, l16 = lane & 15;
  for (int p = blockIdx.x; p < total; p += gridDim.x) {
    __syncthreads();
    int item = work[p];
    int token = item / NCHUNK, c = item % NCHUNK;
    const float4* erow = (const float4*)(enc + (size_t)token * EMB);
    for (int i = threadIdx.x; i < 128; i += 256) ((float4*)se)[i] = erow[i];
    __syncthreads();
    float e2 = esq[token];
    unsigned long long lkey = ~0ULL;
#pragma unroll
    for (int j = 0; j < 4; ++j) {
      int m = c * 64 + wv * 16 + j * 4 + g;
      const float4* trow = (const float4*)(tmp + (size_t)m * EMB);
      double s = 0.0;
#pragma unroll
      for (int k = 0; k < 8; ++k) {
        float4 a = trow[l16 + 16 * k];
        float4 b = ((const float4*)se)[l16 + 16 * k];
        s += (double)a.x * b.x + (double)a.y * b.y
           + (double)a.z * b.z + (double)a.w * b.w;
      }
      s += __shfl_xor(s, 1); s += __shfl_xor(s, 2);
      s += __shfl_xor(s, 4); s += __shfl_xor(s, 8);
      if (l16 == 0) {
        float M  = (float)s;
        float d1 = __fadd_rn(e2, -__fmul_rn(2.0f, M));
        float d2 = __fadd_rn(d1, tsq[m]);            // full dist >= 0: bits monotone
        unsigned long long key =
            ((unsigned long long)__float_as_uint(d2) << 32) | (unsigned)m;
        if (key < lkey) lkey = key;
      }
    }
    if (l16 == 0 && lkey != ~0ULL) atomicMin(&rkey[token], lkey);
  }
}

// ---------- kernel 5: gather f32 rows + zidx as f32 ----------
__global__ void gather_kernel(const float* __restrict__ tmp, const int* __restrict__ bestIdx,
                              const int* __restrict__ flag,
                              const unsigned long long* __restrict__ rkey,
                              float* __restrict__ out) {
  int token = blockIdx.x * 4 + (threadIdx.x >> 6);
  int lane = threadIdx.x & 63;
  int idx = flag[token] ? (int)(unsigned)(rkey[token] & 0xffffffffULL) : bestIdx[token];
  idx = idx < 0 ? 0 : (idx > NEMB - 1 ? NEMB - 1 : idx);
  const float4* src = (const float4*)(tmp + (size_t)idx * EMB) + lane * 2;
  float4* dst = (float4*)(out + (size_t)token * EMB) + lane * 2;
  dst[0] = src[0];
  dst[1] = src[1];
  if (lane == 0) out[(size_t)N_TOK * EMB + token] = (float)idx;
}

extern "C" void kernel_launch(void* const* d_in, const int* in_sizes, int n_in,
                              void* d_out, int out_size, void* d_ws, size_t ws_size,
                              hipStream_t stream) {
  const float* enc = (const float*)d_in[0];
  const float* tmp = (const float*)d_in[1];
  float* out = (float*)d_out;
  char* ws = (char*)d_ws;
  unsigned short* thi = (unsigned short*)ws;                 //  2,097,152 B
  unsigned short* ehi = (unsigned short*)(ws + 2097152);     // 16,777,216 B
  float* tsq      = (float*)(ws + 18874368);                 //      8,192 B
  float* esq      = (float*)(ws + 18882560);                 //     65,536 B
  unsigned long long* keyc = (unsigned long long*)(ws + 18948096); // 4,194,304 B
  unsigned* s2c   = (unsigned*)(ws + 23142400);              //  2,097,152 B
  int*   bestIdx  = (int*)  (ws + 25239552);                 //     65,536 B
  int*   flag     = (int*)  (ws + 25305088);                 //     65,536 B
  unsigned long long* rkey = (unsigned long long*)(ws + 25370624); // 131,072 B
  int*   wcount   = (int*)  (ws + 25501696);                 //         64 B
  int*   work     = (int*)  (ws + 25501760);                 //  2,097,152 B

  prep_kernel  <<<4608,      256, 0, stream>>>(tmp, enc, thi, tsq, ehi, esq, wcount);
  score_kernel <<<2048,      256, 0, stream>>>(ehi, thi, tsq, keyc, s2c);
  merge_kernel <<<N_TOK/256, 256, 0, stream>>>(keyc, s2c, bestIdx, flag, work, wcount, rkey);
  refine_kernel<<<1024,      256, 0, stream>>>(enc, tmp, esq, tsq, work, wcount, rkey);
  gather_kernel<<<N_TOK/4,   256, 0, stream>>>(tmp, bestIdx, flag, rkey, out);
}